// Round 1
// baseline (546.315 us; speedup 1.0000x reference)
//
#include <hip/hip_runtime.h>
#include <math.h>

#define BB 64
#define HH 1024
#define II 128
#define AA 16
#define ECOLS 819           // int(0.8*1024)
#define ALPHA_X 0.2f        // dt/tau_x
#define ALPHA_W 0.02f       // dt/tau_w
#define DTC 0.02f

// -------- Phase 1: recurrent drive + leaky integration + retanh ----------
// grid = B * (H/4) blocks, 256 threads (4 waves); wave w handles row
// i = itile*4 + w of batch b. total[b,i] = sum_j wh[b,i,j]*sign[j]*out[b,j]
// - wh[b,i,i]*sign[i]*out[b,i] + b_h[i] + relu(x)@|W_x|^T + relu(aux)@|W_aux|^T
__global__ __launch_bounds__(256) void phase1(
    const float* __restrict__ x, const float* __restrict__ state,
    const float* __restrict__ output, const float* __restrict__ wh,
    const float* __restrict__ aux_x, const float* __restrict__ Wx,
    const float* __restrict__ Waux, const float* __restrict__ bh,
    float* __restrict__ new_state, float* __restrict__ new_output)
{
    __shared__ float so[HH];     // signed output row for batch b
    __shared__ float xr[II];     // relu(x[b,:])
    __shared__ float auxr[AA];   // relu(aux_x[b,:])

    const int tid   = threadIdx.x;
    const int b     = blockIdx.x >> 8;       // H/4 = 256 row-tiles per batch
    const int itile = blockIdx.x & 255;

    // cooperative load: signed output (float4 per thread)
    {
        float4 o4 = reinterpret_cast<const float4*>(output + (size_t)b * HH)[tid];
        int j = tid * 4;
        so[j + 0] = (j + 0 < ECOLS) ? o4.x : -o4.x;
        so[j + 1] = (j + 1 < ECOLS) ? o4.y : -o4.y;
        so[j + 2] = (j + 2 < ECOLS) ? o4.z : -o4.z;
        so[j + 3] = (j + 3 < ECOLS) ? o4.w : -o4.w;
    }
    if (tid < II)  xr[tid]   = fmaxf(x[b * II + tid], 0.0f);
    if (tid < AA)  auxr[tid] = fmaxf(aux_x[b * AA + tid], 0.0f);
    __syncthreads();

    const int lane = tid & 63;
    const int w    = tid >> 6;
    const int i    = itile * 4 + w;

    const float* whrow = wh + ((size_t)b * HH + i) * HH;

    float acc = 0.0f;
    #pragma unroll
    for (int c = 0; c < 4; ++c) {
        int j = c * 256 + lane * 4;
        float4 a = reinterpret_cast<const float4*>(whrow + j)[0];
        float4 s = reinterpret_cast<const float4*>(so + j)[0];
        acc += a.x * s.x + a.y * s.y + a.z * s.z + a.w * s.w;
    }
    // feedforward: |W_x| (128 cols over 2 iters) and |W_aux| (16 cols)
    const float* wxr = Wx + (size_t)i * II;
    acc += xr[lane]      * fabsf(wxr[lane]);
    acc += xr[lane + 64] * fabsf(wxr[lane + 64]);
    if (lane < AA) acc += auxr[lane] * fabsf(Waux[(size_t)i * AA + lane]);

    // wave reduction (64 lanes)
    #pragma unroll
    for (int off = 32; off > 0; off >>= 1)
        acc += __shfl_xor(acc, off);

    if (lane == 0) {
        // remove diagonal term (mask_h has zero diagonal)
        float total = acc - whrow[i] * so[i] + bh[i];
        float ns = state[b * HH + i] * (1.0f - ALPHA_X) + total * ALPHA_X;
        float no = tanhf(fmaxf(ns, 0.0f));   // retanh
        new_state[b * HH + i]  = ns;
        new_output[b * HH + i] = no;
    }
}

// -------- Phase 2: additive Hebbian plasticity + clip ----------
// grid = B*H blocks (b fastest for W_h/kappa L2 reuse), 256 threads,
// one (b,i) row of 1024 elements per block, float4 per thread.
__global__ __launch_bounds__(256) void phase2(
    const float* __restrict__ wh, const float* __restrict__ da,
    const float* __restrict__ Whh, const float* __restrict__ kappa,
    const float* __restrict__ no, float* __restrict__ nw)
{
    const int b = blockIdx.x & 63;
    const int i = blockIdx.x >> 6;
    const int j = threadIdx.x * 4;

    const size_t rowoff = ((size_t)b * HH + i) * HH;
    const size_t wrow   = (size_t)i * HH;

    float4 wv = reinterpret_cast<const float4*>(wh + rowoff + j)[0];
    float4 wa = reinterpret_cast<const float4*>(Whh + wrow + j)[0];
    float4 ka = reinterpret_cast<const float4*>(kappa + wrow + j)[0];
    float4 nj = reinterpret_cast<const float4*>(no + (size_t)b * HH + j)[0];

    const float c = DTC * da[b] * no[b * HH + i];   // scalar per row

    float4 r;
    r.x = fminf(fmaxf(ALPHA_W * fabsf(wa.x) + (1.0f - ALPHA_W) * wv.x + c * fabsf(ka.x) * nj.x, 0.0f), 1.0f);
    r.y = fminf(fmaxf(ALPHA_W * fabsf(wa.y) + (1.0f - ALPHA_W) * wv.y + c * fabsf(ka.y) * nj.y, 0.0f), 1.0f);
    r.z = fminf(fmaxf(ALPHA_W * fabsf(wa.z) + (1.0f - ALPHA_W) * wv.z + c * fabsf(ka.z) * nj.z, 0.0f), 1.0f);
    r.w = fminf(fmaxf(ALPHA_W * fabsf(wa.w) + (1.0f - ALPHA_W) * wv.w + c * fabsf(ka.w) * nj.w, 0.0f), 1.0f);

    reinterpret_cast<float4*>(nw + rowoff + j)[0] = r;
}

extern "C" void kernel_launch(void* const* d_in, const int* in_sizes, int n_in,
                              void* d_out, int out_size, void* d_ws, size_t ws_size,
                              hipStream_t stream) {
    const float* x      = (const float*)d_in[0];
    const float* state  = (const float*)d_in[1];
    const float* output = (const float*)d_in[2];
    const float* wh     = (const float*)d_in[3];
    const float* da     = (const float*)d_in[4];
    const float* aux_x  = (const float*)d_in[5];
    const float* Wx     = (const float*)d_in[6];
    const float* Waux   = (const float*)d_in[7];
    const float* Whh    = (const float*)d_in[8];
    const float* bh     = (const float*)d_in[9];
    const float* kappa  = (const float*)d_in[10];
    // d_in[11] = mask_h: recomputed analytically (sign + zero diagonal)

    float* out        = (float*)d_out;
    float* new_state  = out;
    float* new_output = out + (size_t)BB * HH;
    float* new_w      = out + (size_t)2 * BB * HH;

    phase1<<<dim3(BB * (HH / 4)), dim3(256), 0, stream>>>(
        x, state, output, wh, aux_x, Wx, Waux, bh, new_state, new_output);

    phase2<<<dim3(BB * HH), dim3(256), 0, stream>>>(
        wh, da, Whh, kappa, new_output, new_w);
}

// Round 2
// 543.882 us; speedup vs baseline: 1.0045x; 1.0045x over previous
//
#include <hip/hip_runtime.h>
#include <math.h>

#define BB 64
#define HH 1024
#define II 128
#define AA 16
#define ECOLS 819           // int(0.8*1024)
#define ALPHA_X 0.2f        // dt/tau_x
#define ALPHA_W 0.02f       // dt/tau_w
#define DTC 0.02f

// -------- Phase 1: recurrent drive + leaky integration + retanh ----------
// grid = B * (H/16) = 4096 blocks, 1024 threads (16 waves); wave w handles
// row i = itile*16 + w of batch b.
// total[b,i] = sum_j wh[b,i,j]*sign[j]*out[b,j] - wh[b,i,i]*sign[i]*out[b,i]
//            + b_h[i] + relu(x)@|W_x|^T + relu(aux)@|W_aux|^T
// Also writes crow[b*H+i] = DT*da[b]*new_output[b,i] for phase2.
__global__ __launch_bounds__(1024) void phase1(
    const float* __restrict__ x, const float* __restrict__ state,
    const float* __restrict__ output, const float* __restrict__ wh,
    const float* __restrict__ da, const float* __restrict__ aux_x,
    const float* __restrict__ Wx, const float* __restrict__ Waux,
    const float* __restrict__ bh,
    float* __restrict__ new_state, float* __restrict__ new_output,
    float* __restrict__ crow)
{
    __shared__ float so[HH];     // signed output row for batch b
    __shared__ float xr[II];     // relu(x[b,:])
    __shared__ float auxr[AA];   // relu(aux_x[b,:])

    const int tid   = threadIdx.x;
    const int b     = blockIdx.x >> 6;       // 64 row-tiles per batch
    const int itile = blockIdx.x & 63;

    {
        float o = output[b * HH + tid];
        so[tid] = (tid < ECOLS) ? o : -o;
    }
    if (tid < II)  xr[tid]   = fmaxf(x[b * II + tid], 0.0f);
    if (tid < AA)  auxr[tid] = fmaxf(aux_x[b * AA + tid], 0.0f);
    __syncthreads();

    const int lane = tid & 63;
    const int w    = tid >> 6;
    const int i    = itile * 16 + w;

    const float* whrow = wh + ((size_t)b * HH + i) * HH;

    float acc = 0.0f;
    #pragma unroll
    for (int c = 0; c < 4; ++c) {
        int j = c * 256 + lane * 4;
        float4 a = reinterpret_cast<const float4*>(whrow + j)[0];
        float4 s = reinterpret_cast<const float4*>(so + j)[0];
        acc += a.x * s.x + a.y * s.y + a.z * s.z + a.w * s.w;
    }
    // feedforward: |W_x| (128 cols over 2 iters) and |W_aux| (16 cols)
    const float* wxr = Wx + (size_t)i * II;
    acc += xr[lane]      * fabsf(wxr[lane]);
    acc += xr[lane + 64] * fabsf(wxr[lane + 64]);
    if (lane < AA) acc += auxr[lane] * fabsf(Waux[(size_t)i * AA + lane]);

    // wave reduction (64 lanes)
    #pragma unroll
    for (int off = 32; off > 0; off >>= 1)
        acc += __shfl_xor(acc, off);

    if (lane == 0) {
        float total = acc - whrow[i] * so[i] + bh[i];
        float ns = state[b * HH + i] * (1.0f - ALPHA_X) + total * ALPHA_X;
        float no = tanhf(fmaxf(ns, 0.0f));   // retanh
        new_state[b * HH + i]  = ns;
        new_output[b * HH + i] = no;
        crow[b * HH + i]       = DTC * da[b] * no;
    }
}

// -------- Phase 2: additive Hebbian plasticity + clip ----------
// Flat grid-stride streaming over all B*H*H/4 float4 elements.
// idx -> j4 = idx & 255; row = idx >> 8 (= b*H + i); i = row & 1023; b = row >> 10.
__global__ __launch_bounds__(256) void phase2(
    const float* __restrict__ wh, const float* __restrict__ Whh,
    const float* __restrict__ kappa, const float* __restrict__ no,
    const float* __restrict__ crow, float* __restrict__ nw)
{
    const int N4 = BB * HH * (HH / 4);       // 16,777,216 float4s
    const int stride = gridDim.x * blockDim.x;
    int idx = blockIdx.x * blockDim.x + threadIdx.x;

    for (; idx < N4; idx += stride) {
        const int j4  = idx & 255;           // H/4 float4s per row
        const int row = idx >> 8;            // b*H + i
        const int i   = row & (HH - 1);
        const int b   = row >> 10;

        float4 wv = reinterpret_cast<const float4*>(wh)[idx];
        float4 wa = reinterpret_cast<const float4*>(Whh)[(i << 8) + j4];
        float4 ka = reinterpret_cast<const float4*>(kappa)[(i << 8) + j4];
        float4 nj = reinterpret_cast<const float4*>(no)[(b << 8) + j4];
        const float c = crow[row];

        float4 r;
        r.x = fminf(fmaxf(ALPHA_W * fabsf(wa.x) + (1.0f - ALPHA_W) * wv.x + c * fabsf(ka.x) * nj.x, 0.0f), 1.0f);
        r.y = fminf(fmaxf(ALPHA_W * fabsf(wa.y) + (1.0f - ALPHA_W) * wv.y + c * fabsf(ka.y) * nj.y, 0.0f), 1.0f);
        r.z = fminf(fmaxf(ALPHA_W * fabsf(wa.z) + (1.0f - ALPHA_W) * wv.z + c * fabsf(ka.z) * nj.z, 0.0f), 1.0f);
        r.w = fminf(fmaxf(ALPHA_W * fabsf(wa.w) + (1.0f - ALPHA_W) * wv.w + c * fabsf(ka.w) * nj.w, 0.0f), 1.0f);

        reinterpret_cast<float4*>(nw)[idx] = r;
    }
}

extern "C" void kernel_launch(void* const* d_in, const int* in_sizes, int n_in,
                              void* d_out, int out_size, void* d_ws, size_t ws_size,
                              hipStream_t stream) {
    const float* x      = (const float*)d_in[0];
    const float* state  = (const float*)d_in[1];
    const float* output = (const float*)d_in[2];
    const float* wh     = (const float*)d_in[3];
    const float* da     = (const float*)d_in[4];
    const float* aux_x  = (const float*)d_in[5];
    const float* Wx     = (const float*)d_in[6];
    const float* Waux   = (const float*)d_in[7];
    const float* Whh    = (const float*)d_in[8];
    const float* bh     = (const float*)d_in[9];
    const float* kappa  = (const float*)d_in[10];
    // d_in[11] = mask_h: recomputed analytically (sign + zero diagonal)

    float* out        = (float*)d_out;
    float* new_state  = out;
    float* new_output = out + (size_t)BB * HH;
    float* new_w      = out + (size_t)2 * BB * HH;
    float* crow       = (float*)d_ws;        // B*H floats = 256 KB scratch

    phase1<<<dim3(BB * (HH / 16)), dim3(1024), 0, stream>>>(
        x, state, output, wh, da, aux_x, Wx, Waux, bh,
        new_state, new_output, crow);

    phase2<<<dim3(8192), dim3(256), 0, stream>>>(
        wh, Whh, kappa, new_output, crow, new_w);
}